// Round 1
// baseline (85.827 us; speedup 1.0000x reference)
//
#include <hip/hip_runtime.h>

#define BB 64
#define SS 512
#define DD 768

// Kernel A: tW[b][d] = sum_k topic[b][k] * W[k][d]
// grid (B, 3), block 256. Topic row staged in LDS; W reads coalesced across d.
__global__ void tw_kernel(const float* __restrict__ topic,
                          const float* __restrict__ W,
                          float* __restrict__ tW) {
    __shared__ float t_s[DD];
    const int b   = blockIdx.x;
    const int c   = blockIdx.y;
    const int tid = threadIdx.x;

    for (int k = tid; k < DD; k += 256) t_s[k] = topic[b * DD + k];
    __syncthreads();

    const int d = c * 256 + tid;
    float acc = 0.f;
#pragma unroll 4
    for (int k = 0; k < DD; ++k) {
        acc = fmaf(t_s[k], W[k * DD + d], acc);
    }
    tW[b * DD + d] = acc;
}

// Kernel B: scores[b][s] = dot(tW[b], seq[b][s]) + bias
// One wave per (b,s). Each lane: 3 float4 loads of seq and tW, FMA, wave reduce.
__global__ void score_kernel(const float* __restrict__ tW,
                             const float* __restrict__ seq,
                             const float* __restrict__ bias,
                             float* __restrict__ scores) {
    const int gwid = (int)((blockIdx.x * blockDim.x + threadIdx.x) >> 6);
    const int lane = threadIdx.x & 63;
    const int b = gwid >> 9;      // / SS
    const int s = gwid & (SS - 1);

    const float4* sp = (const float4*)(seq + ((size_t)b * SS + s) * DD);
    const float4* tp = (const float4*)(tW + (size_t)b * DD);

    float acc = 0.f;
#pragma unroll
    for (int k = 0; k < 3; ++k) {
        const float4 x = sp[lane + k * 64];
        const float4 t = tp[lane + k * 64];
        acc = fmaf(x.x, t.x, acc);
        acc = fmaf(x.y, t.y, acc);
        acc = fmaf(x.z, t.z, acc);
        acc = fmaf(x.w, t.w, acc);
    }
#pragma unroll
    for (int off = 32; off >= 1; off >>= 1) acc += __shfl_xor(acc, off);

    if (lane == 0) scores[gwid] = acc + bias[0];
}

// Kernel C: beta[b] = softmax(scores[b]) over S. One block of 512 per b.
__global__ void softmax_kernel(const float* __restrict__ scores,
                               float* __restrict__ beta) {
    __shared__ float red[8];
    __shared__ float s_m, s_sum;
    const int b   = blockIdx.x;
    const int tid = threadIdx.x;          // 0..511
    const int wid = tid >> 6, lane = tid & 63;

    const float v = scores[b * SS + tid];

    float m = v;
#pragma unroll
    for (int off = 32; off >= 1; off >>= 1) m = fmaxf(m, __shfl_xor(m, off));
    if (lane == 0) red[wid] = m;
    __syncthreads();
    if (tid == 0) {
        float mm = red[0];
#pragma unroll
        for (int i = 1; i < 8; ++i) mm = fmaxf(mm, red[i]);
        s_m = mm;
    }
    __syncthreads();

    const float e = __expf(v - s_m);
    float sum = e;
#pragma unroll
    for (int off = 32; off >= 1; off >>= 1) sum += __shfl_xor(sum, off);
    if (lane == 0) red[wid] = sum;
    __syncthreads();
    if (tid == 0) {
        float ss = 0.f;
#pragma unroll
        for (int i = 0; i < 8; ++i) ss += red[i];
        s_sum = ss;
    }
    __syncthreads();

    beta[b * SS + tid] = e / s_sum;
}

extern "C" void kernel_launch(void* const* d_in, const int* in_sizes, int n_in,
                              void* d_out, int out_size, void* d_ws, size_t ws_size,
                              hipStream_t stream) {
    const float* topic = (const float*)d_in[0];
    const float* seq   = (const float*)d_in[1];
    const float* W     = (const float*)d_in[2];
    const float* bias  = (const float*)d_in[3];
    float* out = (float*)d_out;

    float* tW     = (float*)d_ws;                 // BB*DD floats
    float* scores = tW + (size_t)BB * DD;         // BB*SS floats

    tw_kernel<<<dim3(BB, 3), 256, 0, stream>>>(topic, W, tW);

    const int total_waves = BB * SS;              // one wave per score
    const int blocks = (total_waves * 64) / 256;  // 4 waves per block
    score_kernel<<<blocks, 256, 0, stream>>>(tW, seq, bias, scores);

    softmax_kernel<<<BB, 512, 0, stream>>>(scores, out);
}

// Round 2
// 34.283 us; speedup vs baseline: 2.5035x; 2.5035x over previous
//
#include <hip/hip_runtime.h>

#define BB 64
#define SS 512
#define DD 768

// Kernel A: tW[b][d] = sum_k topic[b][k] * W[k][d]
// grid (B, 12), block 256 (4 waves). Each block: one b, 64 consecutive d's,
// 4-way k-split across waves (192-long chains), LDS reduce.
__global__ void tw_kernel(const float* __restrict__ topic,
                          const float* __restrict__ W,
                          float* __restrict__ tW) {
    __shared__ float t_s[DD];
    __shared__ float red[4][64];
    const int b  = blockIdx.x;
    const int d0 = blockIdx.y * 64;
    const int t  = threadIdx.x;
    const int dl = t & 63;
    const int kg = t >> 6;          // 0..3

    for (int k = t; k < DD; k += 256) t_s[k] = topic[b * DD + k];
    __syncthreads();

    const float* Wp = W + d0 + dl;
    const int k0 = kg * 192;
    float acc = 0.f;
#pragma unroll 8
    for (int k = 0; k < 192; ++k) {
        acc = fmaf(t_s[k0 + k], Wp[(size_t)(k0 + k) * DD], acc);
    }
    red[kg][dl] = acc;
    __syncthreads();

    if (kg == 0) {
        tW[b * DD + d0 + dl] = red[0][dl] + red[1][dl] + red[2][dl] + red[3][dl];
    }
}

// Kernel B: scores[b][s] = dot(tW[b], seq[b][s]) + bias
// One wave per (b,s). Each lane: 3 float4 loads of seq and tW, FMA, wave reduce.
__global__ void score_kernel(const float* __restrict__ tW,
                             const float* __restrict__ seq,
                             const float* __restrict__ bias,
                             float* __restrict__ scores) {
    const int gwid = (int)((blockIdx.x * blockDim.x + threadIdx.x) >> 6);
    const int lane = threadIdx.x & 63;
    const int b = gwid >> 9;      // / SS
    const int s = gwid & (SS - 1);

    const float4* sp = (const float4*)(seq + ((size_t)b * SS + s) * DD);
    const float4* tp = (const float4*)(tW + (size_t)b * DD);

    float acc = 0.f;
#pragma unroll
    for (int k = 0; k < 3; ++k) {
        const float4 x = sp[lane + k * 64];
        const float4 t = tp[lane + k * 64];
        acc = fmaf(x.x, t.x, acc);
        acc = fmaf(x.y, t.y, acc);
        acc = fmaf(x.z, t.z, acc);
        acc = fmaf(x.w, t.w, acc);
    }
#pragma unroll
    for (int off = 32; off >= 1; off >>= 1) acc += __shfl_xor(acc, off);

    if (lane == 0) scores[gwid] = acc + bias[0];
}

// Kernel C: beta[b] = softmax(scores[b]) over S. One block of 512 per b.
__global__ void softmax_kernel(const float* __restrict__ scores,
                               float* __restrict__ beta) {
    __shared__ float red[8];
    __shared__ float s_m, s_sum;
    const int b   = blockIdx.x;
    const int tid = threadIdx.x;          // 0..511
    const int wid = tid >> 6, lane = tid & 63;

    const float v = scores[b * SS + tid];

    float m = v;
#pragma unroll
    for (int off = 32; off >= 1; off >>= 1) m = fmaxf(m, __shfl_xor(m, off));
    if (lane == 0) red[wid] = m;
    __syncthreads();
    if (tid == 0) {
        float mm = red[0];
#pragma unroll
        for (int i = 1; i < 8; ++i) mm = fmaxf(mm, red[i]);
        s_m = mm;
    }
    __syncthreads();

    const float e = __expf(v - s_m);
    float sum = e;
#pragma unroll
    for (int off = 32; off >= 1; off >>= 1) sum += __shfl_xor(sum, off);
    if (lane == 0) red[wid] = sum;
    __syncthreads();
    if (tid == 0) {
        float ss = 0.f;
#pragma unroll
        for (int i = 0; i < 8; ++i) ss += red[i];
        s_sum = ss;
    }
    __syncthreads();

    beta[b * SS + tid] = e / s_sum;
}

extern "C" void kernel_launch(void* const* d_in, const int* in_sizes, int n_in,
                              void* d_out, int out_size, void* d_ws, size_t ws_size,
                              hipStream_t stream) {
    const float* topic = (const float*)d_in[0];
    const float* seq   = (const float*)d_in[1];
    const float* W     = (const float*)d_in[2];
    const float* bias  = (const float*)d_in[3];
    float* out = (float*)d_out;

    float* tW     = (float*)d_ws;                 // BB*DD floats
    float* scores = tW + (size_t)BB * DD;         // BB*SS floats

    tw_kernel<<<dim3(BB, 12), 256, 0, stream>>>(topic, W, tW);

    const int total_waves = BB * SS;              // one wave per score
    const int blocks = (total_waves * 64) / 256;  // 4 waves per block
    score_kernel<<<blocks, 256, 0, stream>>>(tW, seq, bias, scores);

    softmax_kernel<<<BB, 512, 0, stream>>>(scores, out);
}

// Round 4
// 30.426 us; speedup vs baseline: 2.8209x; 1.1268x over previous
//
#include <hip/hip_runtime.h>

#define BB 64
#define SS 512
#define DD 768
#define D4 192   // DD/4

typedef float v4f __attribute__((ext_vector_type(4)));

// Kernel A: tW[b][d] = sum_k topic[b][k] * W[k][d]
// grid (B, 12), block 256. Each block: one b, 64 consecutive d's (16 float4),
// 16-way k-split (48-long chains), float4 W loads, LDS reduce.
__global__ void tw_kernel(const float* __restrict__ topic,
                          const float* __restrict__ W,
                          float* __restrict__ tW) {
    __shared__ float t_s[DD];
    __shared__ float4 red[16][16];
    const int b  = blockIdx.x;
    const int t  = threadIdx.x;
    const int dl = t & 15;            // float4 slot within the 64-d tile
    const int kg = t >> 4;            // 0..15
    const int d4 = blockIdx.y * 16;   // tile start in float4 units

    for (int k = t; k < DD; k += 256) t_s[k] = topic[b * DD + k];
    __syncthreads();

    const float4* __restrict__ W4 = (const float4*)W;  // [DD][D4]
    const int k0 = kg * 48;
    float4 acc = make_float4(0.f, 0.f, 0.f, 0.f);
#pragma unroll 8
    for (int k = 0; k < 48; ++k) {
        const float ts = t_s[k0 + k];
        const float4 w = W4[(size_t)(k0 + k) * D4 + d4 + dl];
        acc.x = fmaf(ts, w.x, acc.x);
        acc.y = fmaf(ts, w.y, acc.y);
        acc.z = fmaf(ts, w.z, acc.z);
        acc.w = fmaf(ts, w.w, acc.w);
    }
    red[kg][dl] = acc;
    __syncthreads();

    if (t < 16) {
        float4 s = red[0][t];
#pragma unroll
        for (int j = 1; j < 16; ++j) {
            const float4 r = red[j][t];
            s.x += r.x; s.y += r.y; s.z += r.z; s.w += r.w;
        }
        ((float4*)tW)[(size_t)b * D4 + d4 + t] = s;
    }
}

// Kernel B: scores[b][s] = dot(tW[b], seq[b][s]) + bias
// One wave per (b,s). seq loads nontemporal (streamed, zero reuse);
// tW loads cached (reused 512x per row).
__global__ void score_kernel(const float* __restrict__ tW,
                             const float* __restrict__ seq,
                             const float* __restrict__ bias,
                             float* __restrict__ scores) {
    const int gwid = (int)((blockIdx.x * blockDim.x + threadIdx.x) >> 6);
    const int lane = threadIdx.x & 63;
    const int b = gwid >> 9;      // / SS
    const int s = gwid & (SS - 1);

    const v4f* sp = (const v4f*)(seq + ((size_t)b * SS + s) * DD);
    const float4* tp = (const float4*)(tW + (size_t)b * DD);

    float acc = 0.f;
#pragma unroll
    for (int k = 0; k < 3; ++k) {
        const v4f x = __builtin_nontemporal_load(sp + lane + k * 64);
        const float4 t = tp[lane + k * 64];
        acc = fmaf(x.x, t.x, acc);
        acc = fmaf(x.y, t.y, acc);
        acc = fmaf(x.z, t.z, acc);
        acc = fmaf(x.w, t.w, acc);
    }
#pragma unroll
    for (int off = 32; off >= 1; off >>= 1) acc += __shfl_xor(acc, off);

    if (lane == 0) scores[gwid] = acc + bias[0];
}

// Kernel C: beta[b] = softmax(scores[b]) over S. One block of 512 per b.
__global__ void softmax_kernel(const float* __restrict__ scores,
                               float* __restrict__ beta) {
    __shared__ float red[8];
    __shared__ float s_m, s_sum;
    const int b   = blockIdx.x;
    const int tid = threadIdx.x;          // 0..511
    const int wid = tid >> 6, lane = tid & 63;

    const float v = scores[b * SS + tid];

    float m = v;
#pragma unroll
    for (int off = 32; off >= 1; off >>= 1) m = fmaxf(m, __shfl_xor(m, off));
    if (lane == 0) red[wid] = m;
    __syncthreads();
    if (tid == 0) {
        float mm = red[0];
#pragma unroll
        for (int i = 1; i < 8; ++i) mm = fmaxf(mm, red[i]);
        s_m = mm;
    }
    __syncthreads();

    const float e = __expf(v - s_m);
    float sum = e;
#pragma unroll
    for (int off = 32; off >= 1; off >>= 1) sum += __shfl_xor(sum, off);
    if (lane == 0) red[wid] = sum;
    __syncthreads();
    if (tid == 0) {
        float ss = 0.f;
#pragma unroll
        for (int i = 0; i < 8; ++i) ss += red[i];
        s_sum = ss;
    }
    __syncthreads();

    beta[b * SS + tid] = e / s_sum;
}

extern "C" void kernel_launch(void* const* d_in, const int* in_sizes, int n_in,
                              void* d_out, int out_size, void* d_ws, size_t ws_size,
                              hipStream_t stream) {
    const float* topic = (const float*)d_in[0];
    const float* seq   = (const float*)d_in[1];
    const float* W     = (const float*)d_in[2];
    const float* bias  = (const float*)d_in[3];
    float* out = (float*)d_out;

    float* tW     = (float*)d_ws;                 // BB*DD floats
    float* scores = tW + (size_t)BB * DD;         // BB*SS floats

    tw_kernel<<<dim3(BB, 12), 256, 0, stream>>>(topic, W, tW);

    const int total_waves = BB * SS;              // one wave per score
    const int blocks = (total_waves * 64) / 256;  // 4 waves per block
    score_kernel<<<blocks, 256, 0, stream>>>(tW, seq, bias, scores);

    softmax_kernel<<<BB, 512, 0, stream>>>(scores, out);
}